// Round 9
// baseline (564.860 us; speedup 1.0000x reference)
//
#include <hip/hip_runtime.h>

#define N_NODES 100000
#define N_GRAPHS 64
#define N_EDGES 600000
#define BN_EPS 1e-5f

// ===========================================================================
// CSR build: deg histogram -> scan -> cursor fill (+graph bounds merged).
// ===========================================================================
__global__ void deg_hist_kernel(const int* __restrict__ dst,
                                int* __restrict__ deg, int n_edges) {
    int e = blockIdx.x * blockDim.x + threadIdx.x;
    if (e < n_edges) atomicAdd(&deg[dst[e]], 1);
}

__global__ void scan1_kernel(const int* __restrict__ deg, int* __restrict__ excl,
                             int* __restrict__ partials, int n) {
    __shared__ int s[1024];
    int i = blockIdx.x * 1024 + threadIdx.x;
    int v = (i < n) ? deg[i] : 0;
    s[threadIdx.x] = v;
    __syncthreads();
    for (int off = 1; off < 1024; off <<= 1) {
        int t = (threadIdx.x >= (unsigned)off) ? s[threadIdx.x - off] : 0;
        __syncthreads();
        s[threadIdx.x] += t;
        __syncthreads();
    }
    if (i < n) excl[i] = s[threadIdx.x] - v;
    if (threadIdx.x == 1023) partials[blockIdx.x] = s[1023];
}

__global__ void scan2_kernel(int* partials, int nb) {
    __shared__ int s[128];
    int t = threadIdx.x;
    int v = (t < nb) ? partials[t] : 0;
    s[t] = v;
    __syncthreads();
    for (int off = 1; off < 128; off <<= 1) {
        int u = (t >= off) ? s[t - off] : 0;
        __syncthreads();
        s[t] += u;
        __syncthreads();
    }
    if (t < nb) partials[t] = s[t] - v;
}

__global__ void scan3_kernel(int* __restrict__ rowptr, const int* __restrict__ partials,
                             int n, int total) {
    int i = blockIdx.x * blockDim.x + threadIdx.x;
    if (i < n) rowptr[i] += partials[i >> 10];
    else if (i == n) rowptr[n] = total;
}

// csr fill + graph bounds in one launch (independent work, thread ranges)
__global__ void fill_bounds_kernel(const int* __restrict__ src, const int* __restrict__ dst,
                                   const int* __restrict__ rowptr, int* __restrict__ cursor,
                                   int* __restrict__ eids, const int* __restrict__ batch,
                                   int* __restrict__ gstart, int n_edges, int n_nodes) {
    int e = blockIdx.x * blockDim.x + threadIdx.x;
    if (e < n_edges) {
        int t = dst[e];
        int pos = rowptr[t] + atomicAdd(&cursor[t], 1);
        eids[pos] = src[e];
    }
    if (e < n_nodes) {
        if (e == 0) {
            for (int g = 0; g <= batch[0]; ++g) gstart[g] = 0;
        } else {
            int b0 = batch[e - 1], b1 = batch[e];
            for (int g = b0 + 1; g <= b1; ++g) gstart[g] = e;
        }
        if (e == n_nodes - 1) {
            for (int g = batch[e] + 1; g <= N_GRAPHS; ++g) gstart[g] = n_nodes;
        }
    }
}

// ===========================================================================
// Prep, all 3 layers in one launch (blockIdx.y = layer).
// ===========================================================================
struct LayerPrep {
    const float *w1, *w2, *b2, *g, *bb, *m, *v;
    float *w1T, *w2sT, *bias2;
    int DIN, DOUT;
};
struct PrepAll { LayerPrep l[3]; };

__global__ void prep_all_kernel(PrepAll pa) {
    LayerPrep P = pa.l[blockIdx.y];
    int i = blockIdx.x * blockDim.x + threadIdx.x;
    if (i < 64 * P.DIN) {
        int j = i / P.DIN, k = i % P.DIN;
        P.w1T[i] = P.w1[k * 64 + j];
    }
    int i2 = i - 64 * P.DIN;
    if (i2 >= 0 && i2 < P.DOUT * 64) {
        int c = i2 / 64, j = i2 % 64;
        float s = P.g[c] * rsqrtf(P.v[c] + BN_EPS);
        P.w2sT[i2] = P.w2[j * P.DOUT + c] * s;
    }
    int i3 = i2 - P.DOUT * 64;
    if (i3 >= 0 && i3 < P.DOUT) {
        float s = P.g[i3] * rsqrtf(P.v[i3] + BN_EPS);
        P.bias2[i3] = (P.b2[i3] - P.m[i3]) * s + P.bb[i3];
    }
}

// ===========================================================================
// pre-GEMM: y = x @ W1_0 (128 -> 64). 64-node tile, 256 threads, NO LDS.
// lane l owns rows {l,l+16,l+32,l+48}; group g=tid>>4 owns cols g*4..+3, so
// weight reads are wave-group-uniform (broadcast, L1-resident 32 KB) and row
// writes cover full 256 B sectors across the 16 groups.
// ===========================================================================
__global__ __launch_bounds__(256, 6)
void pre_gemm_kernel(const float* __restrict__ x, const float* __restrict__ w1T,
                     float* __restrict__ y, int n_nodes) {
    const int tid = threadIdx.x;
    const int g = tid >> 4, l = tid & 15;
    const long base = (long)blockIdx.x * 64;
    const float4* xv = (const float4*)x;
    const float4* gw1 = (const float4*)w1T;   // [j][k]: row j = 32 float4
    long r[4];
    #pragma unroll
    for (int i = 0; i < 4; ++i) {
        long rr = base + l + 16 * i;
        r[i] = (rr < n_nodes) ? rr : (n_nodes - 1);
    }
    float acc[4][4] = {};
    #pragma unroll 4
    for (int k4 = 0; k4 < 32; ++k4) {
        float4 w0 = gw1[(g * 4 + 0) * 32 + k4];
        float4 w1v = gw1[(g * 4 + 1) * 32 + k4];
        float4 w2v = gw1[(g * 4 + 2) * 32 + k4];
        float4 w3v = gw1[(g * 4 + 3) * 32 + k4];
        #pragma unroll
        for (int i = 0; i < 4; ++i) {
            float4 a = xv[r[i] * 32 + k4];
            acc[i][0] = fmaf(a.x, w0.x, fmaf(a.y, w0.y, fmaf(a.z, w0.z, fmaf(a.w, w0.w, acc[i][0]))));
            acc[i][1] = fmaf(a.x, w1v.x, fmaf(a.y, w1v.y, fmaf(a.z, w1v.z, fmaf(a.w, w1v.w, acc[i][1]))));
            acc[i][2] = fmaf(a.x, w2v.x, fmaf(a.y, w2v.y, fmaf(a.z, w2v.z, fmaf(a.w, w2v.w, acc[i][2]))));
            acc[i][3] = fmaf(a.x, w3v.x, fmaf(a.y, w3v.y, fmaf(a.z, w3v.z, fmaf(a.w, w3v.w, acc[i][3]))));
        }
    }
    #pragma unroll
    for (int i = 0; i < 4; ++i) {
        long n = base + l + 16 * i;
        if (n < n_nodes) {
            float4 v = {acc[i][0], acc[i][1], acc[i][2], acc[i][3]};
            *(float4*)(y + n * 64 + g * 4) = v;
        }
    }
}

// ===========================================================================
// Gather a 64-node tile into LDS: sH[nl][.] = relu(y[n] + sum_adj y[s] + b1).
// 16 lanes/node, 4 passes. Reads ONLY the previous layer's buffer (ping-pong
// guarantees it is complete — never the kernel's own output buffer).
// ===========================================================================
#define SS 68
__device__ __forceinline__ void gather_tile_lds(const float* __restrict__ y,
                                                const int* __restrict__ rowptr,
                                                const int* __restrict__ eids,
                                                const float* __restrict__ b1,
                                                float* sH, long base, int n_nodes,
                                                int tid) {
    const float4* yv = (const float4*)y;
    const int f4 = tid & 15;
    const int gidx = tid >> 4;
    const float4 bv = ((const float4*)b1)[f4];
    #pragma unroll
    for (int pass = 0; pass < 4; ++pass) {
        int nl = pass * 16 + gidx;
        long node = base + nl;
        float4 acc = {0.0f, 0.0f, 0.0f, 0.0f};
        if (node < n_nodes) {
            acc = yv[node * 16 + f4];
            int b = rowptr[node], e = rowptr[node + 1];
            int i = b;
            for (; i + 3 < e; i += 4) {
                int s0 = eids[i], s1 = eids[i + 1], s2 = eids[i + 2], s3 = eids[i + 3];
                float4 r0 = yv[(long)s0 * 16 + f4];
                float4 r1 = yv[(long)s1 * 16 + f4];
                float4 r2 = yv[(long)s2 * 16 + f4];
                float4 r3 = yv[(long)s3 * 16 + f4];
                acc.x += (r0.x + r1.x) + (r2.x + r3.x);
                acc.y += (r0.y + r1.y) + (r2.y + r3.y);
                acc.z += (r0.z + r1.z) + (r2.z + r3.z);
                acc.w += (r0.w + r1.w) + (r2.w + r3.w);
            }
            for (; i < e; ++i) {
                int s = eids[i];
                float4 r = yv[(long)s * 16 + f4];
                acc.x += r.x; acc.y += r.y; acc.z += r.z; acc.w += r.w;
            }
        }
        float4 o;
        o.x = fmaxf(acc.x + bv.x, 0.0f);
        o.y = fmaxf(acc.y + bv.y, 0.0f);
        o.z = fmaxf(acc.z + bv.z, 0.0f);
        o.w = fmaxf(acc.w + bv.w, 0.0f);
        *(float4*)&sH[nl * SS + f4 * 4] = o;
    }
}

// ===========================================================================
// Fused mid layer: gather->LDS; h = relu(t@W2s+bias2) (regs); barrier;
// overwrite LDS with h; ynext = h@W1n. Weights broadcast from global (L1).
// LDS = 64*68*4 = 17.4 KB -> wave-capped occupancy. Ping-pong buffers!
// ===========================================================================
__global__ __launch_bounds__(256, 6)
void mlp_mid_kernel(const float* __restrict__ y, const int* __restrict__ rowptr,
                    const int* __restrict__ eids, const float* __restrict__ b1,
                    const float* __restrict__ w2sT, const float* __restrict__ bias2,
                    const float* __restrict__ w1nT, float* __restrict__ ynext,
                    int n_nodes) {
    __shared__ float sH[64 * SS];
    const int tid = threadIdx.x;
    const long base = (long)blockIdx.x * 64;
    gather_tile_lds(y, rowptr, eids, b1, sH, base, n_nodes, tid);
    __syncthreads();

    const int g = tid >> 4, l = tid & 15;
    const float4* gw2 = (const float4*)w2sT;   // [c][j]: row c = 16 float4
    const float4* gw1n = (const float4*)w1nT;  // [j][k]: row j = 16 float4

    // phase A: h[n][c] for rows {l+16i}, cols g*4..+3
    float h[4][4];
    {
        float acc[4][4] = {};
        #pragma unroll 4
        for (int k4 = 0; k4 < 16; ++k4) {
            float4 w0 = gw2[(g * 4 + 0) * 16 + k4];
            float4 w1v = gw2[(g * 4 + 1) * 16 + k4];
            float4 w2v = gw2[(g * 4 + 2) * 16 + k4];
            float4 w3v = gw2[(g * 4 + 3) * 16 + k4];
            #pragma unroll
            for (int i = 0; i < 4; ++i) {
                float4 a = *(const float4*)&sH[(l + 16 * i) * SS + k4 * 4];
                acc[i][0] = fmaf(a.x, w0.x, fmaf(a.y, w0.y, fmaf(a.z, w0.z, fmaf(a.w, w0.w, acc[i][0]))));
                acc[i][1] = fmaf(a.x, w1v.x, fmaf(a.y, w1v.y, fmaf(a.z, w1v.z, fmaf(a.w, w1v.w, acc[i][1]))));
                acc[i][2] = fmaf(a.x, w2v.x, fmaf(a.y, w2v.y, fmaf(a.z, w2v.z, fmaf(a.w, w2v.w, acc[i][2]))));
                acc[i][3] = fmaf(a.x, w3v.x, fmaf(a.y, w3v.y, fmaf(a.z, w3v.z, fmaf(a.w, w3v.w, acc[i][3]))));
            }
        }
        float4 bv = *(const float4*)&bias2[g * 4];
        #pragma unroll
        for (int i = 0; i < 4; ++i) {
            h[i][0] = fmaxf(acc[i][0] + bv.x, 0.0f);
            h[i][1] = fmaxf(acc[i][1] + bv.y, 0.0f);
            h[i][2] = fmaxf(acc[i][2] + bv.z, 0.0f);
            h[i][3] = fmaxf(acc[i][3] + bv.w, 0.0f);
        }
    }
    __syncthreads();  // all phase-A reads of t complete
    #pragma unroll
    for (int i = 0; i < 4; ++i) {
        float4 hv = {h[i][0], h[i][1], h[i][2], h[i][3]};
        *(float4*)&sH[(l + 16 * i) * SS + g * 4] = hv;
    }
    __syncthreads();

    // phase B: ynext[n][c2] = h[n][:] @ w1n[:][c2], cols g*4..+3
    {
        float acc[4][4] = {};
        #pragma unroll 4
        for (int k4 = 0; k4 < 16; ++k4) {
            float4 w0 = gw1n[(g * 4 + 0) * 16 + k4];
            float4 w1v = gw1n[(g * 4 + 1) * 16 + k4];
            float4 w2v = gw1n[(g * 4 + 2) * 16 + k4];
            float4 w3v = gw1n[(g * 4 + 3) * 16 + k4];
            #pragma unroll
            for (int i = 0; i < 4; ++i) {
                float4 a = *(const float4*)&sH[(l + 16 * i) * SS + k4 * 4];
                acc[i][0] = fmaf(a.x, w0.x, fmaf(a.y, w0.y, fmaf(a.z, w0.z, fmaf(a.w, w0.w, acc[i][0]))));
                acc[i][1] = fmaf(a.x, w1v.x, fmaf(a.y, w1v.y, fmaf(a.z, w1v.z, fmaf(a.w, w1v.w, acc[i][1]))));
                acc[i][2] = fmaf(a.x, w2v.x, fmaf(a.y, w2v.y, fmaf(a.z, w2v.z, fmaf(a.w, w2v.w, acc[i][2]))));
                acc[i][3] = fmaf(a.x, w3v.x, fmaf(a.y, w3v.y, fmaf(a.z, w3v.z, fmaf(a.w, w3v.w, acc[i][3]))));
            }
        }
        #pragma unroll
        for (int i = 0; i < 4; ++i) {
            long n = base + l + 16 * i;
            if (n < n_nodes) {
                float4 v = {acc[i][0], acc[i][1], acc[i][2], acc[i][3]};
                *(float4*)(ynext + n * 64 + g * 4) = v;
            }
        }
    }
}

// ===========================================================================
// Fused final layer: gather->LDS; out = relu(t@W2s + bias2), 96 cols (6/group).
// ===========================================================================
__global__ __launch_bounds__(256, 6)
void mlp_final_kernel(const float* __restrict__ y, const int* __restrict__ rowptr,
                      const int* __restrict__ eids, const float* __restrict__ b1,
                      const float* __restrict__ w2sT, const float* __restrict__ bias2,
                      float* __restrict__ out, int n_nodes) {
    __shared__ float sH[64 * SS];
    const int tid = threadIdx.x;
    const long base = (long)blockIdx.x * 64;
    gather_tile_lds(y, rowptr, eids, b1, sH, base, n_nodes, tid);
    __syncthreads();

    const int g = tid >> 4, l = tid & 15;
    const float4* gw2 = (const float4*)w2sT;   // [c][j]: row c = 16 float4
    float acc[4][6] = {};
    #pragma unroll 2
    for (int k4 = 0; k4 < 16; ++k4) {
        float4 wv[6];
        #pragma unroll
        for (int c = 0; c < 6; ++c) wv[c] = gw2[(g * 6 + c) * 16 + k4];
        #pragma unroll
        for (int i = 0; i < 4; ++i) {
            float4 a = *(const float4*)&sH[(l + 16 * i) * SS + k4 * 4];
            #pragma unroll
            for (int c = 0; c < 6; ++c)
                acc[i][c] = fmaf(a.x, wv[c].x, fmaf(a.y, wv[c].y, fmaf(a.z, wv[c].z, fmaf(a.w, wv[c].w, acc[i][c]))));
        }
    }
    float bv[6];
    #pragma unroll
    for (int c = 0; c < 6; ++c) bv[c] = bias2[g * 6 + c];
    #pragma unroll
    for (int i = 0; i < 4; ++i) {
        long n = base + l + 16 * i;
        if (n < n_nodes) {
            float* op = out + n * 96 + g * 6;
            #pragma unroll
            for (int c = 0; c < 6; ++c) op[c] = fmaxf(acc[i][c] + bv[c], 0.0f);
        }
    }
}

// ===========================================================================
// Mean-pool: per-(graph,segment) partials, non-atomic; finalize reduces.
// ===========================================================================
#define POOL_SPLIT 16
__global__ __launch_bounds__(192)
void pool_seg_kernel(const float* __restrict__ h, const int* __restrict__ gstart,
                     float* __restrict__ part) {
    int g = blockIdx.x >> 4;
    int s = blockIdx.x & 15;
    int lo = gstart[g], hi = gstart[g + 1];
    int len = hi - lo;
    int seg = (len + POOL_SPLIT - 1) / POOL_SPLIT;
    int a = lo + s * seg;
    int b = a + seg; if (b > hi) b = hi;

    int f4 = threadIdx.x % 24;
    int chain = threadIdx.x / 24;
    const float4* hv = (const float4*)h;
    float4 acc = {0.0f, 0.0f, 0.0f, 0.0f};
    for (int n = a + chain; n < b; n += 8) {
        float4 v = hv[(long)n * 24 + f4];
        acc.x += v.x; acc.y += v.y; acc.z += v.z; acc.w += v.w;
    }
    __shared__ float4 red[8][24];
    red[chain][f4] = acc;
    __syncthreads();
    if (threadIdx.x < 24) {
        float4 t = red[0][threadIdx.x];
        #pragma unroll
        for (int c = 1; c < 8; ++c) {
            float4 r = red[c][threadIdx.x];
            t.x += r.x; t.y += r.y; t.z += r.z; t.w += r.w;
        }
        *(float4*)&part[((long)blockIdx.x) * 96 + threadIdx.x * 4] = t;
    }
}

__global__ void finalize_kernel(const float* __restrict__ part,
                                const int* __restrict__ gstart,
                                float* __restrict__ out) {
    int i = blockIdx.x * blockDim.x + threadIdx.x;
    if (i >= N_GRAPHS * 96) return;
    int g = i / 96, c = i - g * 96;
    float s = 0.0f;
    #pragma unroll
    for (int k = 0; k < POOL_SPLIT; ++k) s += part[((long)g * POOL_SPLIT + k) * 96 + c];
    float cnt = (float)(gstart[g + 1] - gstart[g]);
    out[i] = s / fmaxf(cnt, 1.0f);
}

// ---------------------------------------------------------------------------
static inline int cdiv_l(long a, int b) { return (int)((a + b - 1) / b); }

extern "C" void kernel_launch(void* const* d_in, const int* in_sizes, int n_in,
                              void* d_out, int out_size, void* d_ws, size_t ws_size,
                              hipStream_t stream) {
    const float* x     = (const float*)d_in[0];
    const int*   ei    = (const int*)d_in[1];
    const int*   src   = ei;
    const int*   dst   = ei + N_EDGES;
    const int*   batch = (const int*)d_in[2];

    const float* P[3][8];
    int p = 3;
    for (int l = 0; l < 3; ++l)
        for (int q = 0; q < 8; ++q)
            P[l][q] = (const float*)d_in[p++];

    const long NP = N_NODES + 64;
    float* ws   = (float*)d_ws;
    float* yA   = ws;               // NP*64 (ping)
    float* yB   = yA + NP * 64;     // NP*64 (pong)
    float* h2   = yB + NP * 64;     // NP*96 (final node features)
    float* q    = h2 + NP * 96;
    float* w1T[3], *w2sT[3], *bias2[3];
    for (int l = 0; l < 3; ++l) {
        w1T[l] = q;   q += 64 * 128;
        w2sT[l] = q;  q += 96 * 64;
        bias2[l] = q; q += 96;
    }
    float* part   = q;                               // 64*16*96
    int* gstart   = (int*)(part + N_GRAPHS * POOL_SPLIT * 96);
    int* deg      = gstart + 72;
    int* cursor   = deg + N_NODES;
    int* partials = cursor + N_NODES;
    int* rowptr   = partials + 128;
    int* eids     = rowptr + (N_NODES + 1);

    const int B = 256;
    const int DIN[3]  = {128, 64, 64};
    const int DOUT[3] = {64, 64, 96};

    // ---- prep (one launch) ----
    PrepAll pa;
    for (int l = 0; l < 3; ++l) {
        pa.l[l].w1 = P[l][0]; pa.l[l].w2 = P[l][2]; pa.l[l].b2 = P[l][3];
        pa.l[l].g = P[l][4];  pa.l[l].bb = P[l][5]; pa.l[l].m = P[l][6];
        pa.l[l].v = P[l][7];
        pa.l[l].w1T = w1T[l]; pa.l[l].w2sT = w2sT[l]; pa.l[l].bias2 = bias2[l];
        pa.l[l].DIN = DIN[l]; pa.l[l].DOUT = DOUT[l];
    }
    dim3 pgrid(cdiv_l(64 * 128 + 96 * 64 + 96, B), 3);
    prep_all_kernel<<<pgrid, B, 0, stream>>>(pa);

    // ---- CSR build + graph bounds ----
    hipMemsetAsync(deg, 0, (size_t)(2 * N_NODES + 128) * sizeof(int), stream);
    deg_hist_kernel<<<cdiv_l(N_EDGES, B), B, 0, stream>>>(dst, deg, N_EDGES);
    int nblk = cdiv_l(N_NODES, 1024);
    scan1_kernel<<<nblk, 1024, 0, stream>>>(deg, rowptr, partials, N_NODES);
    scan2_kernel<<<1, 128, 0, stream>>>(partials, nblk);
    scan3_kernel<<<cdiv_l(N_NODES + 1, B), B, 0, stream>>>(rowptr, partials, N_NODES, N_EDGES);
    fill_bounds_kernel<<<cdiv_l(N_EDGES, B), B, 0, stream>>>(
        src, dst, rowptr, cursor, eids, batch, gstart, N_EDGES, N_NODES);

    const int ntiles = cdiv_l(N_NODES, 64);

    // ---- layers (ping-pong: yA -> yB -> yA -> h2) ----
    pre_gemm_kernel<<<ntiles, 256, 0, stream>>>(x, w1T[0], yA, N_NODES);
    mlp_mid_kernel<<<ntiles, 256, 0, stream>>>(
        yA, rowptr, eids, P[0][1], w2sT[0], bias2[0], w1T[1], yB, N_NODES);
    mlp_mid_kernel<<<ntiles, 256, 0, stream>>>(
        yB, rowptr, eids, P[1][1], w2sT[1], bias2[1], w1T[2], yA, N_NODES);
    mlp_final_kernel<<<ntiles, 256, 0, stream>>>(
        yA, rowptr, eids, P[2][1], w2sT[2], bias2[2], h2, N_NODES);

    // ---- global mean pool ----
    pool_seg_kernel<<<N_GRAPHS * POOL_SPLIT, 192, 0, stream>>>(h2, gstart, part);
    finalize_kernel<<<cdiv_l(N_GRAPHS * 96, B), B, 0, stream>>>(
        part, gstart, (float*)d_out);
}

// Round 10
// 395.054 us; speedup vs baseline: 1.4298x; 1.4298x over previous
//
#include <hip/hip_runtime.h>

#define N_NODES 100000
#define N_GRAPHS 64
#define N_EDGES 600000
#define BN_EPS 1e-5f

typedef unsigned short bf16_t;

// round-to-nearest-even fp32 -> bf16
__device__ __forceinline__ unsigned short f2bf(float f) {
    unsigned int u = __float_as_uint(f);
    u += 0x7FFF + ((u >> 16) & 1);
    return (unsigned short)(u >> 16);
}
// 4 bf16 (packed uint2) -> float4
__device__ __forceinline__ float4 bf2f4(uint2 p) {
    float4 r;
    r.x = __uint_as_float(p.x << 16);
    r.y = __uint_as_float(p.x & 0xFFFF0000u);
    r.z = __uint_as_float(p.y << 16);
    r.w = __uint_as_float(p.y & 0xFFFF0000u);
    return r;
}
__device__ __forceinline__ uint2 pack4(float a, float b, float c, float d) {
    uint2 p;
    p.x = (unsigned)f2bf(a) | ((unsigned)f2bf(b) << 16);
    p.y = (unsigned)f2bf(c) | ((unsigned)f2bf(d) << 16);
    return p;
}

// ===========================================================================
// CSR build: deg histogram -> scan -> cursor fill (+graph bounds merged).
// ===========================================================================
__global__ void deg_hist_kernel(const int* __restrict__ dst,
                                int* __restrict__ deg, int n_edges) {
    int e = blockIdx.x * blockDim.x + threadIdx.x;
    if (e < n_edges) atomicAdd(&deg[dst[e]], 1);
}

__global__ void scan1_kernel(const int* __restrict__ deg, int* __restrict__ excl,
                             int* __restrict__ partials, int n) {
    __shared__ int s[1024];
    int i = blockIdx.x * 1024 + threadIdx.x;
    int v = (i < n) ? deg[i] : 0;
    s[threadIdx.x] = v;
    __syncthreads();
    for (int off = 1; off < 1024; off <<= 1) {
        int t = (threadIdx.x >= (unsigned)off) ? s[threadIdx.x - off] : 0;
        __syncthreads();
        s[threadIdx.x] += t;
        __syncthreads();
    }
    if (i < n) excl[i] = s[threadIdx.x] - v;
    if (threadIdx.x == 1023) partials[blockIdx.x] = s[1023];
}

__global__ void scan2_kernel(int* partials, int nb) {
    __shared__ int s[128];
    int t = threadIdx.x;
    int v = (t < nb) ? partials[t] : 0;
    s[t] = v;
    __syncthreads();
    for (int off = 1; off < 128; off <<= 1) {
        int u = (t >= off) ? s[t - off] : 0;
        __syncthreads();
        s[t] += u;
        __syncthreads();
    }
    if (t < nb) partials[t] = s[t] - v;
}

__global__ void scan3_kernel(int* __restrict__ rowptr, const int* __restrict__ partials,
                             int n, int total) {
    int i = blockIdx.x * blockDim.x + threadIdx.x;
    if (i < n) rowptr[i] += partials[i >> 10];
    else if (i == n) rowptr[n] = total;
}

__global__ void fill_bounds_kernel(const int* __restrict__ src, const int* __restrict__ dst,
                                   const int* __restrict__ rowptr, int* __restrict__ cursor,
                                   int* __restrict__ eids, const int* __restrict__ batch,
                                   int* __restrict__ gstart, int n_edges, int n_nodes) {
    int e = blockIdx.x * blockDim.x + threadIdx.x;
    if (e < n_edges) {
        int t = dst[e];
        int pos = rowptr[t] + atomicAdd(&cursor[t], 1);
        eids[pos] = src[e];
    }
    if (e < n_nodes) {
        if (e == 0) {
            for (int g = 0; g <= batch[0]; ++g) gstart[g] = 0;
        } else {
            int b0 = batch[e - 1], b1 = batch[e];
            for (int g = b0 + 1; g <= b1; ++g) gstart[g] = e;
        }
        if (e == n_nodes - 1) {
            for (int g = batch[e] + 1; g <= N_GRAPHS; ++g) gstart[g] = n_nodes;
        }
    }
}

// ===========================================================================
// Prep, all 3 layers in one launch (blockIdx.y = layer).
// ===========================================================================
struct LayerPrep {
    const float *w1, *w2, *b2, *g, *bb, *m, *v;
    float *w1T, *w2sT, *bias2;
    int DIN, DOUT;
};
struct PrepAll { LayerPrep l[3]; };

__global__ void prep_all_kernel(PrepAll pa) {
    LayerPrep P = pa.l[blockIdx.y];
    int i = blockIdx.x * blockDim.x + threadIdx.x;
    if (i < 64 * P.DIN) {
        int j = i / P.DIN, k = i % P.DIN;
        P.w1T[i] = P.w1[k * 64 + j];
    }
    int i2 = i - 64 * P.DIN;
    if (i2 >= 0 && i2 < P.DOUT * 64) {
        int c = i2 / 64, j = i2 % 64;
        float s = P.g[c] * rsqrtf(P.v[c] + BN_EPS);
        P.w2sT[i2] = P.w2[j * P.DOUT + c] * s;
    }
    int i3 = i2 - P.DOUT * 64;
    if (i3 >= 0 && i3 < P.DOUT) {
        float s = P.g[i3] * rsqrtf(P.v[i3] + BN_EPS);
        P.bias2[i3] = (P.b2[i3] - P.m[i3]) * s + P.bb[i3];
    }
}

// ===========================================================================
// pre-GEMM (R6 structure): y = x @ W1_0 (128 -> 64), output bf16.
// jg = tid&15 owns cols jg*4..+3 (weights from LDS, swizzled);
// ng = tid>>4 owns rows (x read broadcast per 16-lane group, L1-served).
// ===========================================================================
__global__ __launch_bounds__(256)
void pre_gemm_kernel(const float* __restrict__ x, const float* __restrict__ w1T,
                     bf16_t* __restrict__ y, int n_nodes) {
    __shared__ float w1s[64 * 128];
    const int tid = threadIdx.x;
    const long base = (long)blockIdx.x * 64;

    const float4* gw1 = (const float4*)w1T;
    for (int i4 = tid; i4 < 16 * 128; i4 += 256) {
        int row = i4 >> 5, k4 = i4 & 31;
        *(float4*)&w1s[row * 128 + ((k4 ^ ((row >> 2) & 7)) << 2)] = gw1[i4];
    }
    __syncthreads();

    const int jg = tid & 15, ng = tid >> 4, xw = jg & 7;
    const float* wp = &w1s[(jg * 4) * 128];
    const float4* xv = (const float4*)x;
    long r[4];
    #pragma unroll
    for (int i = 0; i < 4; ++i) {
        long rr = base + ng * 4 + i;
        r[i] = (rr < n_nodes) ? rr : (n_nodes - 1);  // clamp: x has no padding
    }
    float acc[4][4] = {};
    #pragma unroll 4
    for (int k4 = 0; k4 < 32; ++k4) {
        const int ko = (k4 ^ xw) << 2;
        float4 w0 = *(const float4*)&wp[0 * 128 + ko];
        float4 w1v = *(const float4*)&wp[1 * 128 + ko];
        float4 w2v = *(const float4*)&wp[2 * 128 + ko];
        float4 w3v = *(const float4*)&wp[3 * 128 + ko];
        #pragma unroll
        for (int i = 0; i < 4; ++i) {
            float4 a = xv[r[i] * 32 + k4];
            acc[i][0] = fmaf(a.x, w0.x, fmaf(a.y, w0.y, fmaf(a.z, w0.z, fmaf(a.w, w0.w, acc[i][0]))));
            acc[i][1] = fmaf(a.x, w1v.x, fmaf(a.y, w1v.y, fmaf(a.z, w1v.z, fmaf(a.w, w1v.w, acc[i][1]))));
            acc[i][2] = fmaf(a.x, w2v.x, fmaf(a.y, w2v.y, fmaf(a.z, w2v.z, fmaf(a.w, w2v.w, acc[i][2]))));
            acc[i][3] = fmaf(a.x, w3v.x, fmaf(a.y, w3v.y, fmaf(a.z, w3v.z, fmaf(a.w, w3v.w, acc[i][3]))));
        }
    }
    #pragma unroll
    for (int i = 0; i < 4; ++i) {
        long n = base + ng * 4 + i;
        if (n < n_nodes) {
            *(uint2*)(y + n * 64 + jg * 4) = pack4(acc[i][0], acc[i][1], acc[i][2], acc[i][3]);
        }
    }
}

// ===========================================================================
// Gather (bf16 rows) + epilogue: t[n] = relu(y[n] + sum_adj y[s] + b1), fp32.
// Row = 128 B; lane f4 reads uint2 (4 bf16). 4 node-chains/wave, unroll x4.
// ===========================================================================
__global__ __launch_bounds__(256)
void gather64_kernel(const bf16_t* __restrict__ y, const int* __restrict__ rowptr,
                     const int* __restrict__ eids, const float* __restrict__ b1,
                     float* __restrict__ t, int n_nodes) {
    int node = blockIdx.x * 16 + (threadIdx.x >> 4);
    if (node >= n_nodes) return;
    int f4 = threadIdx.x & 15;
    const uint2* yv = (const uint2*)y;
    float4 acc = bf2f4(yv[(long)node * 16 + f4]);
    int b = rowptr[node], e = rowptr[node + 1];
    int i = b;
    for (; i + 3 < e; i += 4) {
        int s0 = eids[i], s1 = eids[i + 1], s2 = eids[i + 2], s3 = eids[i + 3];
        uint2 q0 = yv[(long)s0 * 16 + f4];
        uint2 q1 = yv[(long)s1 * 16 + f4];
        uint2 q2 = yv[(long)s2 * 16 + f4];
        uint2 q3 = yv[(long)s3 * 16 + f4];
        float4 r0 = bf2f4(q0), r1 = bf2f4(q1), r2 = bf2f4(q2), r3 = bf2f4(q3);
        acc.x += (r0.x + r1.x) + (r2.x + r3.x);
        acc.y += (r0.y + r1.y) + (r2.y + r3.y);
        acc.z += (r0.z + r1.z) + (r2.z + r3.z);
        acc.w += (r0.w + r1.w) + (r2.w + r3.w);
    }
    for (; i < e; ++i) {
        int s = eids[i];
        float4 r = bf2f4(yv[(long)s * 16 + f4]);
        acc.x += r.x; acc.y += r.y; acc.z += r.z; acc.w += r.w;
    }
    float4 bv = ((const float4*)b1)[f4];
    float4 o;
    o.x = fmaxf(acc.x + bv.x, 0.0f);
    o.y = fmaxf(acc.y + bv.y, 0.0f);
    o.z = fmaxf(acc.z + bv.z, 0.0f);
    o.w = fmaxf(acc.w + bv.w, 0.0f);
    ((float4*)t)[(long)node * 16 + f4] = o;
}

// ===========================================================================
// Fused mid layer (R6 structure): h = relu(t@W2s + bias2); ynext = h @ W1n
// (bf16 out). t read broadcast from global fp32; one LDS weight buffer
// restaged between phases; h round-trips through sT.
// ===========================================================================
__global__ __launch_bounds__(256)
void fused_mid_kernel(const float* __restrict__ t, const float* __restrict__ w2sT,
                      const float* __restrict__ bias2, const float* __restrict__ w1nT,
                      bf16_t* __restrict__ ynext, int n_nodes) {
    constexpr int SS = 68;
    __shared__ float sT[64 * SS];
    __shared__ float wbuf[64 * 64];
    const int tid = threadIdx.x;
    const long base = (long)blockIdx.x * 64;

    const float4* gw2 = (const float4*)w2sT;
    for (int i4 = tid; i4 < 16 * 64; i4 += 256) {
        int row = i4 >> 4, k4 = i4 & 15;
        *(float4*)&wbuf[row * 64 + ((k4 ^ ((row >> 2) & 7)) << 2)] = gw2[i4];
    }
    __syncthreads();

    const int jg = tid & 15, ng = tid >> 4, xw = jg & 7;
    const float4* tv = (const float4*)(t + base * 64);

    // phase 1: h = relu(t @ w2s + bias2)
    float h[4][4];
    {
        const float* wp = &wbuf[(jg * 4) * 64];
        float acc[4][4] = {};
        #pragma unroll 4
        for (int k4 = 0; k4 < 16; ++k4) {
            const int ko = (k4 ^ xw) << 2;
            float4 w0 = *(const float4*)&wp[0 * 64 + ko];
            float4 w1v = *(const float4*)&wp[1 * 64 + ko];
            float4 w2v = *(const float4*)&wp[2 * 64 + ko];
            float4 w3v = *(const float4*)&wp[3 * 64 + ko];
            #pragma unroll
            for (int i = 0; i < 4; ++i) {
                float4 a = tv[(ng * 4 + i) * 16 + k4];
                acc[i][0] = fmaf(a.x, w0.x, fmaf(a.y, w0.y, fmaf(a.z, w0.z, fmaf(a.w, w0.w, acc[i][0]))));
                acc[i][1] = fmaf(a.x, w1v.x, fmaf(a.y, w1v.y, fmaf(a.z, w1v.z, fmaf(a.w, w1v.w, acc[i][1]))));
                acc[i][2] = fmaf(a.x, w2v.x, fmaf(a.y, w2v.y, fmaf(a.z, w2v.z, fmaf(a.w, w2v.w, acc[i][2]))));
                acc[i][3] = fmaf(a.x, w3v.x, fmaf(a.y, w3v.y, fmaf(a.z, w3v.z, fmaf(a.w, w3v.w, acc[i][3]))));
            }
        }
        float4 bv = *(const float4*)&bias2[jg * 4];
        #pragma unroll
        for (int i = 0; i < 4; ++i) {
            h[i][0] = fmaxf(acc[i][0] + bv.x, 0.0f);
            h[i][1] = fmaxf(acc[i][1] + bv.y, 0.0f);
            h[i][2] = fmaxf(acc[i][2] + bv.z, 0.0f);
            h[i][3] = fmaxf(acc[i][3] + bv.w, 0.0f);
        }
    }
    __syncthreads();  // all phase-1 wbuf reads done

    #pragma unroll
    for (int i = 0; i < 4; ++i) {
        float4 hv = {h[i][0], h[i][1], h[i][2], h[i][3]};
        *(float4*)&sT[(ng * 4 + i) * SS + jg * 4] = hv;
    }
    const float4* gw1n = (const float4*)w1nT;
    for (int i4 = tid; i4 < 16 * 64; i4 += 256) {
        int row = i4 >> 4, k4 = i4 & 15;
        *(float4*)&wbuf[row * 64 + ((k4 ^ ((row >> 2) & 7)) << 2)] = gw1n[i4];
    }
    __syncthreads();

    // phase 2: ynext = h @ w1n (bf16 out)
    {
        const float* ap = &sT[(ng * 4) * SS];
        const float* wp = &wbuf[(jg * 4) * 64];
        float acc[4][4] = {};
        #pragma unroll 4
        for (int k4 = 0; k4 < 16; ++k4) {
            const int ko = (k4 ^ xw) << 2;
            float4 w0 = *(const float4*)&wp[0 * 64 + ko];
            float4 w1v = *(const float4*)&wp[1 * 64 + ko];
            float4 w2v = *(const float4*)&wp[2 * 64 + ko];
            float4 w3v = *(const float4*)&wp[3 * 64 + ko];
            #pragma unroll
            for (int i = 0; i < 4; ++i) {
                float4 a = *(const float4*)&ap[i * SS + k4 * 4];
                acc[i][0] = fmaf(a.x, w0.x, fmaf(a.y, w0.y, fmaf(a.z, w0.z, fmaf(a.w, w0.w, acc[i][0]))));
                acc[i][1] = fmaf(a.x, w1v.x, fmaf(a.y, w1v.y, fmaf(a.z, w1v.z, fmaf(a.w, w1v.w, acc[i][1]))));
                acc[i][2] = fmaf(a.x, w2v.x, fmaf(a.y, w2v.y, fmaf(a.z, w2v.z, fmaf(a.w, w2v.w, acc[i][2]))));
                acc[i][3] = fmaf(a.x, w3v.x, fmaf(a.y, w3v.y, fmaf(a.z, w3v.z, fmaf(a.w, w3v.w, acc[i][3]))));
            }
        }
        #pragma unroll
        for (int i = 0; i < 4; ++i) {
            long n = base + ng * 4 + i;
            if (n < n_nodes) {
                *(uint2*)(ynext + n * 64 + jg * 4) = pack4(acc[i][0], acc[i][1], acc[i][2], acc[i][3]);
            }
        }
    }
}

// ===========================================================================
// Fused final layer (R6 structure): out = relu(t@W2s + bias2), 96-wide fp32.
// ===========================================================================
__global__ __launch_bounds__(256)
void fused_final_kernel(const float* __restrict__ t, const float* __restrict__ w2sT,
                        const float* __restrict__ bias2, float* __restrict__ out,
                        int n_nodes) {
    constexpr int CPT = 6;
    __shared__ float w2s[96 * 64];
    const int tid = threadIdx.x;
    const long base = (long)blockIdx.x * 64;

    const float4* gw2 = (const float4*)w2sT;
    for (int i4 = tid; i4 < 96 * 16; i4 += 256) {
        int row = i4 >> 4, k4 = i4 & 15;
        *(float4*)&w2s[row * 64 + ((k4 ^ ((row / CPT) & 7)) << 2)] = gw2[i4];
    }
    __syncthreads();

    const int cg = tid & 15, ng = tid >> 4, xw = cg & 7;
    const float4* tv = (const float4*)(t + base * 64);
    const float* wp = &w2s[(cg * CPT) * 64];
    float acc[4][CPT] = {};
    #pragma unroll 4
    for (int k4 = 0; k4 < 16; ++k4) {
        const int ko = (k4 ^ xw) << 2;
        float4 wv[CPT];
        #pragma unroll
        for (int c = 0; c < CPT; ++c) wv[c] = *(const float4*)&wp[c * 64 + ko];
        #pragma unroll
        for (int i = 0; i < 4; ++i) {
            float4 h = tv[(ng * 4 + i) * 16 + k4];
            #pragma unroll
            for (int c = 0; c < CPT; ++c)
                acc[i][c] = fmaf(h.x, wv[c].x, fmaf(h.y, wv[c].y, fmaf(h.z, wv[c].z, fmaf(h.w, wv[c].w, acc[i][c]))));
        }
    }
    float bv[CPT];
    #pragma unroll
    for (int c = 0; c < CPT; ++c) bv[c] = bias2[cg * CPT + c];
    #pragma unroll
    for (int i = 0; i < 4; ++i) {
        long n = base + ng * 4 + i;
        if (n < n_nodes) {
            float* op = out + n * 96 + cg * CPT;
            #pragma unroll
            for (int c = 0; c < CPT; ++c) op[c] = fmaxf(acc[i][c] + bv[c], 0.0f);
        }
    }
}

// ===========================================================================
// Mean-pool: per-(graph,segment) partials, non-atomic; finalize reduces.
// ===========================================================================
#define POOL_SPLIT 16
__global__ __launch_bounds__(192)
void pool_seg_kernel(const float* __restrict__ h, const int* __restrict__ gstart,
                     float* __restrict__ part) {
    int g = blockIdx.x >> 4;
    int s = blockIdx.x & 15;
    int lo = gstart[g], hi = gstart[g + 1];
    int len = hi - lo;
    int seg = (len + POOL_SPLIT - 1) / POOL_SPLIT;
    int a = lo + s * seg;
    int b = a + seg; if (b > hi) b = hi;

    int f4 = threadIdx.x % 24;
    int chain = threadIdx.x / 24;
    const float4* hv = (const float4*)h;
    float4 acc = {0.0f, 0.0f, 0.0f, 0.0f};
    for (int n = a + chain; n < b; n += 8) {
        float4 v = hv[(long)n * 24 + f4];
        acc.x += v.x; acc.y += v.y; acc.z += v.z; acc.w += v.w;
    }
    __shared__ float4 red[8][24];
    red[chain][f4] = acc;
    __syncthreads();
    if (threadIdx.x < 24) {
        float4 t = red[0][threadIdx.x];
        #pragma unroll
        for (int c = 1; c < 8; ++c) {
            float4 r = red[c][threadIdx.x];
            t.x += r.x; t.y += r.y; t.z += r.z; t.w += r.w;
        }
        *(float4*)&part[((long)blockIdx.x) * 96 + threadIdx.x * 4] = t;
    }
}

__global__ void finalize_kernel(const float* __restrict__ part,
                                const int* __restrict__ gstart,
                                float* __restrict__ out) {
    int i = blockIdx.x * blockDim.x + threadIdx.x;
    if (i >= N_GRAPHS * 96) return;
    int g = i / 96, c = i - g * 96;
    float s = 0.0f;
    #pragma unroll
    for (int k = 0; k < POOL_SPLIT; ++k) s += part[((long)g * POOL_SPLIT + k) * 96 + c];
    float cnt = (float)(gstart[g + 1] - gstart[g]);
    out[i] = s / fmaxf(cnt, 1.0f);
}

// ---------------------------------------------------------------------------
static inline int cdiv_l(long a, int b) { return (int)((a + b - 1) / b); }

extern "C" void kernel_launch(void* const* d_in, const int* in_sizes, int n_in,
                              void* d_out, int out_size, void* d_ws, size_t ws_size,
                              hipStream_t stream) {
    const float* x     = (const float*)d_in[0];
    const int*   ei    = (const int*)d_in[1];
    const int*   src   = ei;
    const int*   dst   = ei + N_EDGES;
    const int*   batch = (const int*)d_in[2];

    const float* P[3][8];
    int p = 3;
    for (int l = 0; l < 3; ++l)
        for (int q = 0; q < 8; ++q)
            P[l][q] = (const float*)d_in[p++];

    const long NP = N_NODES + 64;
    char* wsb   = (char*)d_ws;
    bf16_t* yA  = (bf16_t*)wsb;                       // NP*64 bf16 (ping)
    bf16_t* yB  = yA + NP * 64;                       // NP*64 bf16 (pong)
    float* gB   = (float*)(yB + NP * 64);             // NP*64 fp32 (t)
    float* h2   = gB + NP * 64;                       // NP*96 fp32
    float* q    = h2 + NP * 96;
    float* w1T[3], *w2sT[3], *bias2[3];
    for (int l = 0; l < 3; ++l) {
        w1T[l] = q;   q += 64 * 128;
        w2sT[l] = q;  q += 96 * 64;
        bias2[l] = q; q += 96;
    }
    float* part   = q;                                // 64*16*96
    int* gstart   = (int*)(part + N_GRAPHS * POOL_SPLIT * 96);
    int* deg      = gstart + 72;
    int* cursor   = deg + N_NODES;
    int* partials = cursor + N_NODES;
    int* rowptr   = partials + 128;
    int* eids     = rowptr + (N_NODES + 1);

    const int B = 256;
    const int DIN[3]  = {128, 64, 64};
    const int DOUT[3] = {64, 64, 96};

    // ---- prep (one launch) ----
    PrepAll pa;
    for (int l = 0; l < 3; ++l) {
        pa.l[l].w1 = P[l][0]; pa.l[l].w2 = P[l][2]; pa.l[l].b2 = P[l][3];
        pa.l[l].g = P[l][4];  pa.l[l].bb = P[l][5]; pa.l[l].m = P[l][6];
        pa.l[l].v = P[l][7];
        pa.l[l].w1T = w1T[l]; pa.l[l].w2sT = w2sT[l]; pa.l[l].bias2 = bias2[l];
        pa.l[l].DIN = DIN[l]; pa.l[l].DOUT = DOUT[l];
    }
    dim3 pgrid(cdiv_l(64 * 128 + 96 * 64 + 96, B), 3);
    prep_all_kernel<<<pgrid, B, 0, stream>>>(pa);

    // ---- CSR build + graph bounds ----
    hipMemsetAsync(deg, 0, (size_t)(2 * N_NODES + 128) * sizeof(int), stream);
    deg_hist_kernel<<<cdiv_l(N_EDGES, B), B, 0, stream>>>(dst, deg, N_EDGES);
    int nblk = cdiv_l(N_NODES, 1024);
    scan1_kernel<<<nblk, 1024, 0, stream>>>(deg, rowptr, partials, N_NODES);
    scan2_kernel<<<1, 128, 0, stream>>>(partials, nblk);
    scan3_kernel<<<cdiv_l(N_NODES + 1, B), B, 0, stream>>>(rowptr, partials, N_NODES, N_EDGES);
    fill_bounds_kernel<<<cdiv_l(N_EDGES, B), B, 0, stream>>>(
        src, dst, rowptr, cursor, eids, batch, gstart, N_EDGES, N_NODES);

    const int ntiles = cdiv_l(N_NODES, 64);
    const int ngather = cdiv_l(N_NODES, 16);

    // ---- layer 0 ----
    pre_gemm_kernel<<<ntiles, 256, 0, stream>>>(x, w1T[0], yA, N_NODES);
    gather64_kernel<<<ngather, 256, 0, stream>>>(yA, rowptr, eids, P[0][1], gB, N_NODES);
    fused_mid_kernel<<<ntiles, 256, 0, stream>>>(
        gB, w2sT[0], bias2[0], w1T[1], yB, N_NODES);
    // ---- layer 1 ----
    gather64_kernel<<<ngather, 256, 0, stream>>>(yB, rowptr, eids, P[1][1], gB, N_NODES);
    fused_mid_kernel<<<ntiles, 256, 0, stream>>>(
        gB, w2sT[1], bias2[1], w1T[2], yA, N_NODES);
    // ---- layer 2 ----
    gather64_kernel<<<ngather, 256, 0, stream>>>(yA, rowptr, eids, P[2][1], gB, N_NODES);
    fused_final_kernel<<<ntiles, 256, 0, stream>>>(
        gB, w2sT[2], bias2[2], h2, N_NODES);

    // ---- global mean pool ----
    pool_seg_kernel<<<N_GRAPHS * POOL_SPLIT, 192, 0, stream>>>(h2, gstart, part);
    finalize_kernel<<<cdiv_l(N_GRAPHS * 96, B), B, 0, stream>>>(
        part, gstart, (float*)d_out);
}